// Round 1
// baseline (201.669 us; speedup 1.0000x reference)
//
#include <hip/hip_runtime.h>
#include <cstdint>
#include <cstddef>

// KAN policy network, fp32.
// Shapes: x(16384,1024), Wb1(1024,5), Ws1(1024,5,10), Wb2(5,5), Ws2(5,5,10),
//         Wb3(5,64), Ws3(5,64,10). out = softmax over 64, (16384,64) fp32.
// Knots: t_i = i*0.4 - 3 in v-units v = (x+3)*2.5 -> integer knots 0..15.

#define NROWS 16384
#define IN1   1024
#define WPACK 48      // packed floats per i: 5 outs x 8 slots (k=2..9) + 5 Wb + 3 pad
#define NCHUNK 8      // i-split factor for layer 1
#define RGROUPS (NROWS / 64)

// ---------------------------------------------------------------- K0: pack W1
__global__ void k0_pack(const float* __restrict__ Wb1, const float* __restrict__ Ws1,
                        float* __restrict__ w1p) {
  int e = blockIdx.x * 256 + threadIdx.x;
  if (e >= IN1 * WPACK) return;
  int i = e / WPACK;
  int c = e - i * WPACK;
  float v = 0.0f;
  if (c < 40) {
    int o = c >> 3, k = (c & 7) + 2;            // k = 2..9 only reachable for x in [0,1)
    v = Ws1[(i * 5 + o) * 10 + k];
  } else if (c < 45) {
    v = Wb1[i * 5 + (c - 40)];
  }
  w1p[e] = v;
}

// -------------------------------------------------- quintic cardinal pieces
// N_r(u) = sum_m C[m][r] u^m / 120 ; r=0..5 are the 6 nonzero bases on a span.
#define C120(a) ((a) / 120.0f)

__device__ __forceinline__ void kan1_elem(float x, const float* __restrict__ w,
                                          float& a0, float& a1, float& a2,
                                          float& a3, float& a4) {
  float v  = fmaf(x, 2.5f, 7.5f);     // knot units; x in [0,1) -> v in [7.5,10)
  float jf = floorf(v);               // 7, 8 or 9
  float u  = v - jf;                  // [0,1)
  // Horner, /120 folded into coefficients
  float N0 = fmaf(fmaf(fmaf(fmaf(fmaf(C120(-1.f), u, C120(5.f)),  u, C120(-10.f)), u, C120(10.f)),  u, C120(-5.f)),  u, C120(1.f));
  float N1 = fmaf(fmaf(fmaf(fmaf(fmaf(C120(5.f),  u, C120(-20.f)), u, C120(20.f)),  u, C120(20.f)),  u, C120(-50.f)), u, C120(26.f));
  float N2 = fmaf(fmaf(fmaf(fmaf(fmaf(C120(-10.f),u, C120(30.f)),  u, C120(0.f)),   u, C120(-60.f)), u, C120(0.f)),   u, C120(66.f));
  float N3 = fmaf(fmaf(fmaf(fmaf(fmaf(C120(10.f), u, C120(-20.f)), u, C120(-20.f)), u, C120(20.f)),  u, C120(50.f)),  u, C120(26.f));
  float N4 = fmaf(fmaf(fmaf(fmaf(fmaf(C120(-5.f), u, C120(5.f)),   u, C120(10.f)),  u, C120(10.f)),  u, C120(5.f)),   u, C120(1.f));
  float u2 = u * u;
  float N5 = u2 * u2 * u * C120(1.f);
  // scatter into slots s = (j-7) + r ; slot s <-> basis k = s+2
  bool e0 = jf < 7.5f;   // j == 7
  bool e2 = jf > 8.5f;   // j == 9
  float B0 = e0 ? N0 : 0.0f;
  float B1 = e0 ? N1 : (e2 ? 0.0f : N0);
  float B2 = e0 ? N2 : (e2 ? N0 : N1);
  float B3 = e0 ? N3 : (e2 ? N1 : N2);
  float B4 = e0 ? N4 : (e2 ? N2 : N3);
  float B5v= e0 ? N5 : (e2 ? N3 : N4);
  float B6 = e0 ? 0.0f : (e2 ? N4 : N5);
  float B7 = e2 ? N5 : 0.0f;
  // silu
  float si = x / (1.0f + __expf(-x));
  // accumulate 5 outputs (weights are wave-uniform -> scalar operands)
  a0 = fmaf(si, w[40], a0);
  a0 = fmaf(B0, w[0], a0); a0 = fmaf(B1, w[1], a0); a0 = fmaf(B2, w[2], a0); a0 = fmaf(B3, w[3], a0);
  a0 = fmaf(B4, w[4], a0); a0 = fmaf(B5v, w[5], a0); a0 = fmaf(B6, w[6], a0); a0 = fmaf(B7, w[7], a0);
  a1 = fmaf(si, w[41], a1);
  a1 = fmaf(B0, w[8], a1); a1 = fmaf(B1, w[9], a1); a1 = fmaf(B2, w[10], a1); a1 = fmaf(B3, w[11], a1);
  a1 = fmaf(B4, w[12], a1); a1 = fmaf(B5v, w[13], a1); a1 = fmaf(B6, w[14], a1); a1 = fmaf(B7, w[15], a1);
  a2 = fmaf(si, w[42], a2);
  a2 = fmaf(B0, w[16], a2); a2 = fmaf(B1, w[17], a2); a2 = fmaf(B2, w[18], a2); a2 = fmaf(B3, w[19], a2);
  a2 = fmaf(B4, w[20], a2); a2 = fmaf(B5v, w[21], a2); a2 = fmaf(B6, w[22], a2); a2 = fmaf(B7, w[23], a2);
  a3 = fmaf(si, w[43], a3);
  a3 = fmaf(B0, w[24], a3); a3 = fmaf(B1, w[25], a3); a3 = fmaf(B2, w[26], a3); a3 = fmaf(B3, w[27], a3);
  a3 = fmaf(B4, w[28], a3); a3 = fmaf(B5v, w[29], a3); a3 = fmaf(B6, w[30], a3); a3 = fmaf(B7, w[31], a3);
  a4 = fmaf(si, w[44], a4);
  a4 = fmaf(B0, w[32], a4); a4 = fmaf(B1, w[33], a4); a4 = fmaf(B2, w[34], a4); a4 = fmaf(B3, w[35], a4);
  a4 = fmaf(B4, w[36], a4); a4 = fmaf(B5v, w[37], a4); a4 = fmaf(B6, w[38], a4); a4 = fmaf(B7, w[39], a4);
}

// ---------------------------------------------------------------- K1: layer 1
// grid = RGROUPS * NCHUNK blocks of 256. block (rg, c): rows rg*64..+63,
// i in [c*128, c*128+128), 4 waves x 32 i each. lane <-> row.
__global__ __launch_bounds__(256, 4) void k1_layer1(const float* __restrict__ x,
                                                    const float* __restrict__ w1p,
                                                    float* __restrict__ hp) {
  __shared__ float part[4 * 64 * 5];
  int tid  = threadIdx.x;
  int wv   = tid >> 6, lane = tid & 63;
  int bid  = blockIdx.x;
  int rg   = bid >> 3, c = bid & 7;
  int i0   = c * 128 + wv * 32;
  const float* xp = x + (size_t)(rg * 64 + lane) * IN1 + i0;
  const float* wb = w1p + (size_t)i0 * WPACK;
  float a0 = 0.f, a1 = 0.f, a2 = 0.f, a3 = 0.f, a4 = 0.f;
#pragma unroll 2
  for (int s = 0; s < 8; ++s) {
    float4 xv = reinterpret_cast<const float4*>(xp)[s];
    const float* w = wb + (size_t)s * 4 * WPACK;
    kan1_elem(xv.x, w,             a0, a1, a2, a3, a4);
    kan1_elem(xv.y, w + WPACK,     a0, a1, a2, a3, a4);
    kan1_elem(xv.z, w + 2 * WPACK, a0, a1, a2, a3, a4);
    kan1_elem(xv.w, w + 3 * WPACK, a0, a1, a2, a3, a4);
  }
  float* pr = part + (wv * 64 + lane) * 5;
  pr[0] = a0; pr[1] = a1; pr[2] = a2; pr[3] = a3; pr[4] = a4;
  __syncthreads();
  for (int t = tid; t < 320; t += 256) {
    float s = part[t] + part[t + 320] + part[t + 640] + part[t + 960];
    hp[(size_t)bid * 320 + t] = s;     // slab per block: [row][o]
  }
}

// ------------------------------------------- generic bases (reference-style)
__device__ __forceinline__ void bases10(float xv, float* bb) {
  float v = fmaf(xv, 2.5f, 7.5f);
  float b[15];
#pragma unroll
  for (int j = 0; j < 15; ++j)
    b[j] = (v >= (float)j && v < (float)(j + 1)) ? 1.0f : 0.0f;
#pragma unroll
  for (int d = 1; d <= 5; ++d) {
    const float inv = 1.0f / (float)d;
#pragma unroll
    for (int j = 0; j + d < 15; ++j) {
      float left  = (v - (float)j) * inv;
      float right = ((float)(j + d + 1) - v) * inv;
      b[j] = left * b[j] + right * b[j + 1];   // reads old b[j], old b[j+1]
    }
  }
#pragma unroll
  for (int k = 0; k < 10; ++k) bb[k] = b[k];
}

// ---------------------------------------------------------------- K2: tail
// block <-> rowgroup of 64 rows. Reduce partials, layers 2+3, softmax.
__global__ void k2_tail(const float* __restrict__ hp,
                        const float* __restrict__ Wb2, const float* __restrict__ Ws2,
                        const float* __restrict__ Wb3, const float* __restrict__ Ws3,
                        float* __restrict__ out) {
  __shared__ float lh[64][5];
  __shared__ float lsi[64][5];
  __shared__ float lb[64][5][10];
  __shared__ float llog[64][65];   // padded
  __shared__ float lms[64][2];
  int tid = threadIdx.x;
  int rg  = blockIdx.x;

  // Phase A: sum the 8 chunk partials -> h1 ; silu(h1)
  for (int u = tid; u < 320; u += 256) {
    float s = 0.f;
#pragma unroll
    for (int c = 0; c < NCHUNK; ++c)
      s += hp[(size_t)(rg * NCHUNK + c) * 320 + u];
    int row = u / 5, o = u - row * 5;
    lh[row][o]  = s;
    lsi[row][o] = s / (1.0f + __expf(-s));
  }
  __syncthreads();

  // Phase B: bases of h1
  for (int u = tid; u < 320; u += 256) {
    int row = u / 5, i = u - row * 5;
    float bb[10];
    bases10(lh[row][i], bb);
#pragma unroll
    for (int k = 0; k < 10; ++k) lb[row][i][k] = bb[k];
  }
  __syncthreads();

  // Phase C: h2 = silu(h1)@Wb2 + einsum(b1, Ws2)  (write lh; lh not read here)
  for (int u = tid; u < 320; u += 256) {
    int row = u / 5, o = u - row * 5;
    float acc = 0.f;
#pragma unroll
    for (int i = 0; i < 5; ++i) {
      acc = fmaf(lsi[row][i], Wb2[i * 5 + o], acc);
#pragma unroll
      for (int k = 0; k < 10; ++k)
        acc = fmaf(lb[row][i][k], Ws2[(i * 5 + o) * 10 + k], acc);
    }
    lh[row][o] = acc;
  }
  __syncthreads();

  // Phase D: silu(h2), bases of h2
  for (int u = tid; u < 320; u += 256) {
    int row = u / 5, i = u - row * 5;
    float h = lh[row][i];
    lsi[row][i] = h / (1.0f + __expf(-h));
    float bb[10];
    bases10(h, bb);
#pragma unroll
    for (int k = 0; k < 10; ++k) lb[row][i][k] = bb[k];
  }
  __syncthreads();

  // Phase E: logits. thread -> (o = tid&63, 16 rows)
  {
    int o  = tid & 63;
    int r0 = (tid >> 6) * 16;
    float lg[16];
#pragma unroll
    for (int rr = 0; rr < 16; ++rr) lg[rr] = 0.f;
#pragma unroll
    for (int i = 0; i < 5; ++i) {
      float wbv = Wb3[i * 64 + o];
      float w[10];
#pragma unroll
      for (int k = 0; k < 10; ++k) w[k] = Ws3[(i * 64 + o) * 10 + k];
#pragma unroll
      for (int rr = 0; rr < 16; ++rr) {
        int row = r0 + rr;
        lg[rr] = fmaf(lsi[row][i], wbv, lg[rr]);
#pragma unroll
        for (int k = 0; k < 10; ++k)
          lg[rr] = fmaf(lb[row][i][k], w[k], lg[rr]);
      }
    }
#pragma unroll
    for (int rr = 0; rr < 16; ++rr) llog[r0 + rr][o] = lg[rr];
  }
  __syncthreads();

  // Phase F: per-row max & sum
  if (tid < 64) {
    float m = -1e30f;
#pragma unroll
    for (int o = 0; o < 64; ++o) m = fmaxf(m, llog[tid][o]);
    float ssum = 0.f;
#pragma unroll
    for (int o = 0; o < 64; ++o) ssum += __expf(llog[tid][o] - m);
    lms[tid][0] = m;
    lms[tid][1] = 1.0f / ssum;
  }
  __syncthreads();

  // Phase G: probabilities, coalesced
#pragma unroll
  for (int uu = 0; uu < 16; ++uu) {
    int u = tid + uu * 256;          // 0..4095
    int row = u >> 6, o = u & 63;
    out[(size_t)(rg * 64 + row) * 64 + o] =
        __expf(llog[row][o] - lms[row][0]) * lms[row][1];
  }
}

// ---------------------------------------------------------------- launch
extern "C" void kernel_launch(void* const* d_in, const int* in_sizes, int n_in,
                              void* d_out, int out_size, void* d_ws, size_t ws_size,
                              hipStream_t stream) {
  const float* x   = (const float*)d_in[0];
  const float* Wb1 = (const float*)d_in[1];
  const float* Ws1 = (const float*)d_in[2];
  const float* Wb2 = (const float*)d_in[3];
  const float* Ws2 = (const float*)d_in[4];
  const float* Wb3 = (const float*)d_in[5];
  const float* Ws3 = (const float*)d_in[6];
  float* out = (float*)d_out;

  float* w1p = (float*)d_ws;                       // 1024*48 floats = 192 KiB
  float* hp  = w1p + (size_t)IN1 * WPACK;          // 2048*320 floats = 2.5 MiB

  hipLaunchKernelGGL(k0_pack, dim3((IN1 * WPACK) / 256), dim3(256), 0, stream,
                     Wb1, Ws1, w1p);
  hipLaunchKernelGGL(k1_layer1, dim3(RGROUPS * NCHUNK), dim3(256), 0, stream,
                     x, w1p, hp);
  hipLaunchKernelGGL(k2_tail, dim3(RGROUPS), dim3(256), 0, stream,
                     hp, Wb2, Ws2, Wb3, Ws3, out);
}

// Round 3
// 201.081 us; speedup vs baseline: 1.0029x; 1.0029x over previous
//
#include <hip/hip_runtime.h>
#include <cstdint>
#include <cstddef>

// KAN policy network, fp32.
// x(16384,1024), Wb1(1024,5), Ws1(1024,5,10), Wb2(5,5), Ws2(5,5,10),
// Wb3(5,64), Ws3(5,64,10). out = softmax64, (16384,64) fp32.
// v-units: v = (x+3)*2.5, integer knots 0..15.

#define NROWS 16384
#define IN1   1024
#define WPACK 48      // 5 outs x 8 slots (k=2..9) + 5 Wb + 3 pad
#define NCHUNK 8
#define RGROUPS (NROWS / 64)

// ---------------------------------------------------------------- K0: pack W1
__global__ void k0_pack(const float* __restrict__ Wb1, const float* __restrict__ Ws1,
                        float* __restrict__ w1p) {
  int e = blockIdx.x * 256 + threadIdx.x;
  if (e >= IN1 * WPACK) return;
  int i = e / WPACK;
  int c = e - i * WPACK;
  float v = 0.0f;
  if (c < 40) {
    int o = c >> 3, k = (c & 7) + 2;
    v = Ws1[(i * 5 + o) * 10 + k];
  } else if (c < 45) {
    v = Wb1[i * 5 + (c - 40)];
  }
  w1p[e] = v;
}

// -------------------------------------------------- quintic cardinal pieces
#define C120(a) ((a) / 120.0f)

__device__ __forceinline__ void kan1_elem(float x, const float* __restrict__ w,
                                          float& a0, float& a1, float& a2,
                                          float& a3, float& a4) {
  float v  = fmaf(x, 2.5f, 7.5f);     // x in [0,1) -> v in [7.5,10)
  float jf = floorf(v);               // 7, 8 or 9
  float u  = v - jf;
  float N0 = fmaf(fmaf(fmaf(fmaf(fmaf(C120(-1.f), u, C120(5.f)),  u, C120(-10.f)), u, C120(10.f)),  u, C120(-5.f)),  u, C120(1.f));
  float N1 = fmaf(fmaf(fmaf(fmaf(fmaf(C120(5.f),  u, C120(-20.f)), u, C120(20.f)),  u, C120(20.f)),  u, C120(-50.f)), u, C120(26.f));
  float N2 = fmaf(fmaf(fmaf(fmaf(fmaf(C120(-10.f),u, C120(30.f)),  u, C120(0.f)),   u, C120(-60.f)), u, C120(0.f)),   u, C120(66.f));
  float N3 = fmaf(fmaf(fmaf(fmaf(fmaf(C120(10.f), u, C120(-20.f)), u, C120(-20.f)), u, C120(20.f)),  u, C120(50.f)),  u, C120(26.f));
  float N4 = fmaf(fmaf(fmaf(fmaf(fmaf(C120(-5.f), u, C120(5.f)),   u, C120(10.f)),  u, C120(10.f)),  u, C120(5.f)),   u, C120(1.f));
  float u2 = u * u;
  float N5 = u2 * u2 * u * C120(1.f);
  bool e0 = jf < 7.5f;   // j == 7
  bool e2 = jf > 8.5f;   // j == 9
  float B0 = e0 ? N0 : 0.0f;
  float B1 = e0 ? N1 : (e2 ? 0.0f : N0);
  float B2 = e0 ? N2 : (e2 ? N0 : N1);
  float B3 = e0 ? N3 : (e2 ? N1 : N2);
  float B4 = e0 ? N4 : (e2 ? N2 : N3);
  float B5v= e0 ? N5 : (e2 ? N3 : N4);
  float B6 = e0 ? 0.0f : (e2 ? N4 : N5);
  float B7 = e2 ? N5 : 0.0f;
  float si = x / (1.0f + __expf(-x));
  a0 = fmaf(si, w[40], a0);
  a0 = fmaf(B0, w[0], a0); a0 = fmaf(B1, w[1], a0); a0 = fmaf(B2, w[2], a0); a0 = fmaf(B3, w[3], a0);
  a0 = fmaf(B4, w[4], a0); a0 = fmaf(B5v, w[5], a0); a0 = fmaf(B6, w[6], a0); a0 = fmaf(B7, w[7], a0);
  a1 = fmaf(si, w[41], a1);
  a1 = fmaf(B0, w[8], a1); a1 = fmaf(B1, w[9], a1); a1 = fmaf(B2, w[10], a1); a1 = fmaf(B3, w[11], a1);
  a1 = fmaf(B4, w[12], a1); a1 = fmaf(B5v, w[13], a1); a1 = fmaf(B6, w[14], a1); a1 = fmaf(B7, w[15], a1);
  a2 = fmaf(si, w[42], a2);
  a2 = fmaf(B0, w[16], a2); a2 = fmaf(B1, w[17], a2); a2 = fmaf(B2, w[18], a2); a2 = fmaf(B3, w[19], a2);
  a2 = fmaf(B4, w[20], a2); a2 = fmaf(B5v, w[21], a2); a2 = fmaf(B6, w[22], a2); a2 = fmaf(B7, w[23], a2);
  a3 = fmaf(si, w[43], a3);
  a3 = fmaf(B0, w[24], a3); a3 = fmaf(B1, w[25], a3); a3 = fmaf(B2, w[26], a3); a3 = fmaf(B3, w[27], a3);
  a3 = fmaf(B4, w[28], a3); a3 = fmaf(B5v, w[29], a3); a3 = fmaf(B6, w[30], a3); a3 = fmaf(B7, w[31], a3);
  a4 = fmaf(si, w[44], a4);
  a4 = fmaf(B0, w[32], a4); a4 = fmaf(B1, w[33], a4); a4 = fmaf(B2, w[34], a4); a4 = fmaf(B3, w[35], a4);
  a4 = fmaf(B4, w[36], a4); a4 = fmaf(B5v, w[37], a4); a4 = fmaf(B6, w[38], a4); a4 = fmaf(B7, w[39], a4);
}

// ---------------------------------------------------------------- K1: layer 1
// grid = RGROUPS*NCHUNK blocks of 256. block (rg,c): rows rg*64..+63,
// i in [c*128, +128), 4 waves x 32 i. lane <-> row. Weight addresses are
// forced wave-uniform via readfirstlane so the 45 weight loads scalarize
// (s_load; SGPR operands in the FMAs) -- no per-lane VMEM, no addr VALU.
__global__ __launch_bounds__(256, 4) void k1_layer1(const float* __restrict__ x,
                                                    const float* __restrict__ w1p,
                                                    float* __restrict__ hp) {
  __shared__ float part[4 * 320];
  int tid  = threadIdx.x;
  int wv   = tid >> 6, lane = tid & 63;
  int bid  = blockIdx.x;
  int rg   = bid >> 3, c = bid & 7;
  int wvu  = __builtin_amdgcn_readfirstlane(wv);   // wave-uniform wave id
  int i0   = c * 128 + wvu * 32;
  const float* xp = x + (size_t)(rg * 64 + lane) * IN1 + i0;
  const float* wb = w1p + (size_t)i0 * WPACK;      // uniform -> scalar loads
  float a0 = 0.f, a1 = 0.f, a2 = 0.f, a3 = 0.f, a4 = 0.f;
#pragma unroll 2
  for (int s = 0; s < 8; ++s) {
    float4 xv = reinterpret_cast<const float4*>(xp)[s];
    const float* w = wb + (size_t)s * 4 * WPACK;
    kan1_elem(xv.x, w,             a0, a1, a2, a3, a4);
    kan1_elem(xv.y, w + WPACK,     a0, a1, a2, a3, a4);
    kan1_elem(xv.z, w + 2 * WPACK, a0, a1, a2, a3, a4);
    kan1_elem(xv.w, w + 3 * WPACK, a0, a1, a2, a3, a4);
  }
  float* pr = part + wv * 320 + lane * 5;
  pr[0] = a0; pr[1] = a1; pr[2] = a2; pr[3] = a3; pr[4] = a4;
  __syncthreads();
  // store slab in [o][row] layout: t = o*64 + row  (coalesced reads in K2)
  for (int t = tid; t < 320; t += 256) {
    int row = t & 63, o = t >> 6;
    float s = part[row * 5 + o] + part[320 + row * 5 + o] +
              part[640 + row * 5 + o] + part[960 + row * 5 + o];
    hp[(size_t)bid * 320 + t] = s;
  }
}

// ------------------------------------------- generic bases (reference-style)
__device__ __forceinline__ void bases10(float xv, float* bb) {
  float v = fmaf(xv, 2.5f, 7.5f);
  float b[15];
#pragma unroll
  for (int j = 0; j < 15; ++j)
    b[j] = (v >= (float)j && v < (float)(j + 1)) ? 1.0f : 0.0f;
#pragma unroll
  for (int d = 1; d <= 5; ++d) {
    const float inv = 1.0f / (float)d;
#pragma unroll
    for (int j = 0; j + d < 15; ++j) {
      float left  = (v - (float)j) * inv;
      float right = ((float)(j + d + 1) - v) * inv;
      b[j] = left * b[j] + right * b[j + 1];
    }
  }
#pragma unroll
  for (int k = 0; k < 10; ++k) bb[k] = b[k];
}

// ---------------------------------------------------------------- K2: tail
// One row per thread, registers end-to-end. block=128 (2 waves), grid=128.
// Logits go through LDS (runtime o-index would force register arrays to
// scratch otherwise).
__global__ __launch_bounds__(128, 2) void k2_tail(const float* __restrict__ hp,
                        const float* __restrict__ Wb2, const float* __restrict__ Ws2,
                        const float* __restrict__ Wb3, const float* __restrict__ Ws3,
                        float* __restrict__ out) {
  __shared__ float lg[64 * 128];     // [o][tid]
  int tid = threadIdx.x;
  int row = blockIdx.x * 128 + tid;
  int rg  = row >> 6, r6 = row & 63;

  // reduce the 8 chunk partials -> h1 (same sequential order as before)
  float h1[5];
#pragma unroll
  for (int o = 0; o < 5; ++o) {
    float s = 0.f;
#pragma unroll
    for (int c = 0; c < NCHUNK; ++c)
      s += hp[(size_t)(rg * NCHUNK + c) * 320 + o * 64 + r6];
    h1[o] = s;
  }

  float si1[5], b1[5][10];
#pragma unroll
  for (int i = 0; i < 5; ++i) {
    si1[i] = h1[i] / (1.0f + __expf(-h1[i]));
    bases10(h1[i], b1[i]);
  }

  float h2[5];
#pragma unroll
  for (int o = 0; o < 5; ++o) {
    float acc = 0.f;
#pragma unroll
    for (int i = 0; i < 5; ++i) {
      acc = fmaf(si1[i], Wb2[i * 5 + o], acc);
#pragma unroll
      for (int k = 0; k < 10; ++k)
        acc = fmaf(b1[i][k], Ws2[(i * 5 + o) * 10 + k], acc);
    }
    h2[o] = acc;
  }

  float si2[5], b2[5][10];
#pragma unroll
  for (int i = 0; i < 5; ++i) {
    si2[i] = h2[i] / (1.0f + __expf(-h2[i]));
    bases10(h2[i], b2[i]);
  }

  // logits -> LDS (o loop NOT unrolled: small code, weights from scalar cache)
  for (int o = 0; o < 64; ++o) {
    float acc = 0.f;
#pragma unroll
    for (int i = 0; i < 5; ++i) {
      acc = fmaf(si2[i], Wb3[i * 64 + o], acc);
#pragma unroll
      for (int k = 0; k < 10; ++k)
        acc = fmaf(b2[i][k], Ws3[(i * 64 + o) * 10 + k], acc);
    }
    lg[o * 128 + tid] = acc;
  }

  // softmax over the 64 logits (per thread/row)
  float m = -1e30f;
  for (int o = 0; o < 64; ++o) m = fmaxf(m, lg[o * 128 + tid]);
  float ssum = 0.f;
  for (int o = 0; o < 64; ++o) ssum += __expf(lg[o * 128 + tid] - m);
  float inv = 1.0f / ssum;
  float* op = out + (size_t)row * 64;
  for (int o = 0; o < 64; ++o)
    op[o] = __expf(lg[o * 128 + tid] - m) * inv;
}

// ---------------------------------------------------------------- launch
extern "C" void kernel_launch(void* const* d_in, const int* in_sizes, int n_in,
                              void* d_out, int out_size, void* d_ws, size_t ws_size,
                              hipStream_t stream) {
  const float* x   = (const float*)d_in[0];
  const float* Wb1 = (const float*)d_in[1];
  const float* Ws1 = (const float*)d_in[2];
  const float* Wb2 = (const float*)d_in[3];
  const float* Ws2 = (const float*)d_in[4];
  const float* Wb3 = (const float*)d_in[5];
  const float* Ws3 = (const float*)d_in[6];
  float* out = (float*)d_out;

  float* w1p = (float*)d_ws;                       // 1024*48 floats = 192 KiB
  float* hp  = w1p + (size_t)IN1 * WPACK;          // 2048*320 floats = 2.5 MiB

  hipLaunchKernelGGL(k0_pack, dim3((IN1 * WPACK) / 256), dim3(256), 0, stream,
                     Wb1, Ws1, w1p);
  hipLaunchKernelGGL(k1_layer1, dim3(RGROUPS * NCHUNK), dim3(256), 0, stream,
                     x, w1p, hp);
  hipLaunchKernelGGL(k2_tail, dim3(NROWS / 128), dim3(128), 0, stream,
                     hp, Wb2, Ws2, Wb3, Ws3, out);
}

// Round 4
// 158.071 us; speedup vs baseline: 1.2758x; 1.2721x over previous
//
#include <hip/hip_runtime.h>
#include <cstdint>
#include <cstddef>

// KAN policy network, fp32.
// x(16384,1024), Wb1(1024,5), Ws1(1024,5,10), Wb2(5,5), Ws2(5,5,10),
// Wb3(5,64), Ws3(5,64,10). out = softmax64, (16384,64) fp32.
// v-units: v = (x+3)*2.5, integer knots 0..15.

#define NROWS 16384
#define IN1   1024
#define WPACK 48      // 5 outs x 8 slots (k=2..9) + 5 Wb + 3 pad
#define NCHUNK 8
#define RGROUPS (NROWS / 64)

// ---------------------------------------------------------------- K0: pack W1
__global__ void k0_pack(const float* __restrict__ Wb1, const float* __restrict__ Ws1,
                        float* __restrict__ w1p) {
  int e = blockIdx.x * 256 + threadIdx.x;
  if (e >= IN1 * WPACK) return;
  int i = e / WPACK;
  int c = e - i * WPACK;
  float v = 0.0f;
  if (c < 40) {
    int o = c >> 3, k = (c & 7) + 2;
    v = Ws1[(i * 5 + o) * 10 + k];
  } else if (c < 45) {
    v = Wb1[i * 5 + (c - 40)];
  }
  w1p[e] = v;
}

// -------------------------------------------------- quintic cardinal pieces
#define C120(a) ((a) / 120.0f)

__device__ __forceinline__ void kan1_elem(float x, const float* __restrict__ w,
                                          float& a0, float& a1, float& a2,
                                          float& a3, float& a4) {
  float v  = fmaf(x, 2.5f, 7.5f);     // x in [0,1) -> v in [7.5,10)
  float jf = floorf(v);               // 7, 8 or 9
  float u  = v - jf;
  float N0 = fmaf(fmaf(fmaf(fmaf(fmaf(C120(-1.f), u, C120(5.f)),  u, C120(-10.f)), u, C120(10.f)),  u, C120(-5.f)),  u, C120(1.f));
  float N1 = fmaf(fmaf(fmaf(fmaf(fmaf(C120(5.f),  u, C120(-20.f)), u, C120(20.f)),  u, C120(20.f)),  u, C120(-50.f)), u, C120(26.f));
  float N2 = fmaf(fmaf(fmaf(fmaf(fmaf(C120(-10.f),u, C120(30.f)),  u, C120(0.f)),   u, C120(-60.f)), u, C120(0.f)),   u, C120(66.f));
  float N3 = fmaf(fmaf(fmaf(fmaf(fmaf(C120(10.f), u, C120(-20.f)), u, C120(-20.f)), u, C120(20.f)),  u, C120(50.f)),  u, C120(26.f));
  float N4 = fmaf(fmaf(fmaf(fmaf(fmaf(C120(-5.f), u, C120(5.f)),   u, C120(10.f)),  u, C120(10.f)),  u, C120(5.f)),   u, C120(1.f));
  float u2 = u * u;
  float N5 = u2 * u2 * u * C120(1.f);
  bool e0 = jf < 7.5f;   // j == 7
  bool e2 = jf > 8.5f;   // j == 9
  float B0 = e0 ? N0 : 0.0f;
  float B1 = e0 ? N1 : (e2 ? 0.0f : N0);
  float B2 = e0 ? N2 : (e2 ? N0 : N1);
  float B3 = e0 ? N3 : (e2 ? N1 : N2);
  float B4 = e0 ? N4 : (e2 ? N2 : N3);
  float B5v= e0 ? N5 : (e2 ? N3 : N4);
  float B6 = e0 ? 0.0f : (e2 ? N4 : N5);
  float B7 = e2 ? N5 : 0.0f;
  float si = x / (1.0f + __expf(-x));
  a0 = fmaf(si, w[40], a0);
  a0 = fmaf(B0, w[0], a0); a0 = fmaf(B1, w[1], a0); a0 = fmaf(B2, w[2], a0); a0 = fmaf(B3, w[3], a0);
  a0 = fmaf(B4, w[4], a0); a0 = fmaf(B5v, w[5], a0); a0 = fmaf(B6, w[6], a0); a0 = fmaf(B7, w[7], a0);
  a1 = fmaf(si, w[41], a1);
  a1 = fmaf(B0, w[8], a1); a1 = fmaf(B1, w[9], a1); a1 = fmaf(B2, w[10], a1); a1 = fmaf(B3, w[11], a1);
  a1 = fmaf(B4, w[12], a1); a1 = fmaf(B5v, w[13], a1); a1 = fmaf(B6, w[14], a1); a1 = fmaf(B7, w[15], a1);
  a2 = fmaf(si, w[42], a2);
  a2 = fmaf(B0, w[16], a2); a2 = fmaf(B1, w[17], a2); a2 = fmaf(B2, w[18], a2); a2 = fmaf(B3, w[19], a2);
  a2 = fmaf(B4, w[20], a2); a2 = fmaf(B5v, w[21], a2); a2 = fmaf(B6, w[22], a2); a2 = fmaf(B7, w[23], a2);
  a3 = fmaf(si, w[43], a3);
  a3 = fmaf(B0, w[24], a3); a3 = fmaf(B1, w[25], a3); a3 = fmaf(B2, w[26], a3); a3 = fmaf(B3, w[27], a3);
  a3 = fmaf(B4, w[28], a3); a3 = fmaf(B5v, w[29], a3); a3 = fmaf(B6, w[30], a3); a3 = fmaf(B7, w[31], a3);
  a4 = fmaf(si, w[44], a4);
  a4 = fmaf(B0, w[32], a4); a4 = fmaf(B1, w[33], a4); a4 = fmaf(B2, w[34], a4); a4 = fmaf(B3, w[35], a4);
  a4 = fmaf(B4, w[36], a4); a4 = fmaf(B5v, w[37], a4); a4 = fmaf(B6, w[38], a4); a4 = fmaf(B7, w[39], a4);
}

// ---------------------------------------------------------------- K1: layer 1
// grid = RGROUPS*NCHUNK blocks of 256. block (rg,c): rows rg*64..+63,
// i in [c*128, +128), 4 waves x 32 i. lane <-> row. Weight addresses are
// forced wave-uniform via readfirstlane so the 45 weight loads scalarize.
__global__ __launch_bounds__(256, 4) void k1_layer1(const float* __restrict__ x,
                                                    const float* __restrict__ w1p,
                                                    float* __restrict__ hp) {
  __shared__ float part[4 * 320];
  int tid  = threadIdx.x;
  int wv   = tid >> 6, lane = tid & 63;
  int bid  = blockIdx.x;
  int rg   = bid >> 3, c = bid & 7;
  int wvu  = __builtin_amdgcn_readfirstlane(wv);   // wave-uniform wave id
  int i0   = c * 128 + wvu * 32;
  const float* xp = x + (size_t)(rg * 64 + lane) * IN1 + i0;
  const float* wb = w1p + (size_t)i0 * WPACK;      // uniform -> scalar loads
  float a0 = 0.f, a1 = 0.f, a2 = 0.f, a3 = 0.f, a4 = 0.f;
#pragma unroll 2
  for (int s = 0; s < 8; ++s) {
    float4 xv = reinterpret_cast<const float4*>(xp)[s];
    const float* w = wb + (size_t)s * 4 * WPACK;
    kan1_elem(xv.x, w,             a0, a1, a2, a3, a4);
    kan1_elem(xv.y, w + WPACK,     a0, a1, a2, a3, a4);
    kan1_elem(xv.z, w + 2 * WPACK, a0, a1, a2, a3, a4);
    kan1_elem(xv.w, w + 3 * WPACK, a0, a1, a2, a3, a4);
  }
  float* pr = part + wv * 320 + lane * 5;
  pr[0] = a0; pr[1] = a1; pr[2] = a2; pr[3] = a3; pr[4] = a4;
  __syncthreads();
  // store slab in [o][row] layout: t = o*64 + row  (coalesced reads in K2)
  for (int t = tid; t < 320; t += 256) {
    int row = t & 63, o = t >> 6;
    float s = part[row * 5 + o] + part[320 + row * 5 + o] +
              part[640 + row * 5 + o] + part[960 + row * 5 + o];
    hp[(size_t)bid * 320 + t] = s;
  }
}

// ------------------------------------------- generic bases (reference-style)
__device__ __forceinline__ void bases10(float xv, float* bb) {
  float v = fmaf(xv, 2.5f, 7.5f);
  float b[15];
#pragma unroll
  for (int j = 0; j < 15; ++j)
    b[j] = (v >= (float)j && v < (float)(j + 1)) ? 1.0f : 0.0f;
#pragma unroll
  for (int d = 1; d <= 5; ++d) {
    const float inv = 1.0f / (float)d;
#pragma unroll
    for (int j = 0; j + d < 15; ++j) {
      float left  = (v - (float)j) * inv;
      float right = ((float)(j + d + 1) - v) * inv;
      b[j] = left * b[j] + right * b[j + 1];
    }
  }
#pragma unroll
  for (int k = 0; k < 10; ++k) bb[k] = b[k];
}

// ---------------------------------------------------------------- K2: tail
// 256 blocks x 256 threads; block <-> 64 rows. All phases parallel over the
// full block; LDS strides padded so accesses are <=2-way (free).
__global__ __launch_bounds__(256) void k2_tail(const float* __restrict__ hp,
                        const float* __restrict__ Wb2, const float* __restrict__ Ws2,
                        const float* __restrict__ Wb3, const float* __restrict__ Ws3,
                        float* __restrict__ out) {
  __shared__ float lsi1[64 * 5];
  __shared__ float lb1 [64 * 55];   // [row][i*11+k], stride 55 (odd-ish, 2-way max)
  __shared__ float lsi2[64 * 5];
  __shared__ float lb2 [64 * 55];
  __shared__ float llog[64 * 65];   // [row][o], stride 65
  __shared__ float lred[4 * 64];
  __shared__ float lmx [64];
  __shared__ float linv[64];
  int tid = threadIdx.x;
  int rg  = blockIdx.x;

  // Phase A: reduce 8 chunk partials -> h1 ; silu + bases -> LDS. (row,i)-parallel.
  for (int t = tid; t < 320; t += 256) {
    int row = t & 63, i = t >> 6;
    float s = 0.f;
#pragma unroll
    for (int c = 0; c < NCHUNK; ++c)
      s += hp[(size_t)(rg * NCHUNK + c) * 320 + t];
    lsi1[row * 5 + i] = s / (1.0f + __expf(-s));
    float bb[10];
    bases10(s, bb);
#pragma unroll
    for (int k = 0; k < 10; ++k) lb1[row * 55 + i * 11 + k] = bb[k];
  }
  __syncthreads();

  // Phase B: layer 2 (row,o)-parallel; then silu+bases of own h2 value.
  for (int t = tid; t < 320; t += 256) {
    int row = t & 63, o = t >> 6;
    float acc = 0.f;
#pragma unroll
    for (int i = 0; i < 5; ++i) {
      acc = fmaf(lsi1[row * 5 + i], Wb2[i * 5 + o], acc);
#pragma unroll
      for (int k = 0; k < 10; ++k)
        acc = fmaf(lb1[row * 55 + i * 11 + k], Ws2[(i * 5 + o) * 10 + k], acc);
    }
    lsi2[row * 5 + o] = acc / (1.0f + __expf(-acc));
    float bb[10];
    bases10(acc, bb);
#pragma unroll
    for (int k = 0; k < 10; ++k) lb2[row * 55 + o * 11 + k] = bb[k];
  }
  __syncthreads();

  // Phase C: logits. thread -> (o = tid&63, 16 rows). LDS reads are row-
  // uniform per wave -> broadcast (free).
  {
    int o  = tid & 63;
    int r0 = (tid >> 6) * 16;
    float lg[16];
#pragma unroll
    for (int rr = 0; rr < 16; ++rr) lg[rr] = 0.f;
#pragma unroll
    for (int i = 0; i < 5; ++i) {
      float wbv = Wb3[i * 64 + o];
      float w[10];
#pragma unroll
      for (int k = 0; k < 10; ++k) w[k] = Ws3[(i * 64 + o) * 10 + k];
#pragma unroll
      for (int rr = 0; rr < 16; ++rr) {
        int row = r0 + rr;
        lg[rr] = fmaf(lsi2[row * 5 + i], wbv, lg[rr]);
#pragma unroll
        for (int k = 0; k < 10; ++k)
          lg[rr] = fmaf(lb2[row * 55 + i * 11 + k], w[k], lg[rr]);
      }
    }
#pragma unroll
    for (int rr = 0; rr < 16; ++rr) llog[(r0 + rr) * 65 + o] = lg[rr];
  }
  __syncthreads();

  // Phase D: softmax, 4 threads per row (q = tid>>6 scans 16 outs).
  int q = tid >> 6, row = tid & 63;
  {
    float m = -1e30f;
#pragma unroll
    for (int oo = 0; oo < 16; ++oo)
      m = fmaxf(m, llog[row * 65 + q * 16 + oo]);
    lred[q * 64 + row] = m;
  }
  __syncthreads();
  if (tid < 64) {
    float m = fmaxf(fmaxf(lred[tid], lred[64 + tid]),
                    fmaxf(lred[128 + tid], lred[192 + tid]));
    lmx[tid] = m;
  }
  __syncthreads();
  {
    float m = lmx[row];
    float s = 0.f;
#pragma unroll
    for (int oo = 0; oo < 16; ++oo) {
      int idx = row * 65 + q * 16 + oo;
      float e = __expf(llog[idx] - m);
      llog[idx] = e;
      s += e;
    }
    lred[q * 64 + row] = s;
  }
  __syncthreads();
  if (tid < 64) {
    float s = lred[tid] + lred[64 + tid] + lred[128 + tid] + lred[192 + tid];
    linv[tid] = 1.0f / s;
  }
  __syncthreads();
  // coalesced store: each wave writes one row's 64 contiguous floats per step
#pragma unroll
  for (int uu = 0; uu < 16; ++uu) {
    int u = tid + uu * 256;
    int r = u >> 6, o = u & 63;
    out[(size_t)(rg * 64 + r) * 64 + o] = llog[r * 65 + o] * linv[r];
  }
}

// ---------------------------------------------------------------- launch
extern "C" void kernel_launch(void* const* d_in, const int* in_sizes, int n_in,
                              void* d_out, int out_size, void* d_ws, size_t ws_size,
                              hipStream_t stream) {
  const float* x   = (const float*)d_in[0];
  const float* Wb1 = (const float*)d_in[1];
  const float* Ws1 = (const float*)d_in[2];
  const float* Wb2 = (const float*)d_in[3];
  const float* Ws2 = (const float*)d_in[4];
  const float* Wb3 = (const float*)d_in[5];
  const float* Ws3 = (const float*)d_in[6];
  float* out = (float*)d_out;

  float* w1p = (float*)d_ws;                       // 1024*48 floats = 192 KiB
  float* hp  = w1p + (size_t)IN1 * WPACK;          // 2048*320 floats = 2.5 MiB

  hipLaunchKernelGGL(k0_pack, dim3((IN1 * WPACK) / 256), dim3(256), 0, stream,
                     Wb1, Ws1, w1p);
  hipLaunchKernelGGL(k1_layer1, dim3(RGROUPS * NCHUNK), dim3(256), 0, stream,
                     x, w1p, hp);
  hipLaunchKernelGGL(k2_tail, dim3(RGROUPS), dim3(256), 0, stream,
                     hp, Wb2, Ws2, Wb3, Ws3, out);
}

// Round 5
// 148.270 us; speedup vs baseline: 1.3601x; 1.0661x over previous
//
#include <hip/hip_runtime.h>
#include <cstdint>
#include <cstddef>

// KAN policy network, fp32.
// x(16384,1024), Wb1(1024,5), Ws1(1024,5,10), Wb2(5,5), Ws2(5,5,10),
// Wb3(5,64), Ws3(5,64,10). out = softmax64, (16384,64) fp32.
// v-units: v = (x+3)*2.5, integer knots 0..15.

#define NROWS 16384
#define IN1   1024
#define WPACK 48      // 5 outs x 8 slots (k=2..9) + 5 Wb + 3 pad
#define NCHUNK 8
#define RGROUPS (NROWS / 64)

// ---------------------------------------------------------------- K0: pack W1
__global__ void k0_pack(const float* __restrict__ Wb1, const float* __restrict__ Ws1,
                        float* __restrict__ w1p) {
  int e = blockIdx.x * 256 + threadIdx.x;
  if (e >= IN1 * WPACK) return;
  int i = e / WPACK;
  int c = e - i * WPACK;
  float v = 0.0f;
  if (c < 40) {
    int o = c >> 3, k = (c & 7) + 2;
    v = Ws1[(i * 5 + o) * 10 + k];
  } else if (c < 45) {
    v = Wb1[i * 5 + (c - 40)];
  }
  w1p[e] = v;
}

// -------------------------------------------------- quintic cardinal pieces
#define C120(a) ((a) / 120.0f)

__device__ __forceinline__ void kan1_elem(float x, const float* __restrict__ w,
                                          float& a0, float& a1, float& a2,
                                          float& a3, float& a4) {
  float v  = fmaf(x, 2.5f, 7.5f);            // x in [0,1) -> v in [7.5,10)
  float u  = __builtin_amdgcn_fractf(v);     // v - floor(v), 1 inst
  float N0 = fmaf(fmaf(fmaf(fmaf(fmaf(C120(-1.f), u, C120(5.f)),  u, C120(-10.f)), u, C120(10.f)),  u, C120(-5.f)),  u, C120(1.f));
  float N1 = fmaf(fmaf(fmaf(fmaf(fmaf(C120(5.f),  u, C120(-20.f)), u, C120(20.f)),  u, C120(20.f)),  u, C120(-50.f)), u, C120(26.f));
  float N2 = fmaf(fmaf(fmaf(fmaf(fmaf(C120(-10.f),u, C120(30.f)),  u, C120(0.f)),   u, C120(-60.f)), u, C120(0.f)),   u, C120(66.f));
  float N3 = fmaf(fmaf(fmaf(fmaf(fmaf(C120(10.f), u, C120(-20.f)), u, C120(-20.f)), u, C120(20.f)),  u, C120(50.f)),  u, C120(26.f));
  float N4 = fmaf(fmaf(fmaf(fmaf(fmaf(C120(-5.f), u, C120(5.f)),   u, C120(10.f)),  u, C120(10.f)),  u, C120(5.f)),   u, C120(1.f));
  float u2 = u * u;
  float N5 = u2 * u2 * u * C120(1.f);
  bool e0 = v < 8.0f;    // j == 7
  bool e2 = v >= 9.0f;   // j == 9
  float B0 = e0 ? N0 : 0.0f;
  float B1 = e0 ? N1 : (e2 ? 0.0f : N0);
  float B2 = e0 ? N2 : (e2 ? N0 : N1);
  float B3 = e0 ? N3 : (e2 ? N1 : N2);
  float B4 = e0 ? N4 : (e2 ? N2 : N3);
  float B5v= e0 ? N5 : (e2 ? N3 : N4);
  float B6 = e0 ? 0.0f : (e2 ? N4 : N5);
  float B7 = e2 ? N5 : 0.0f;
  // silu via rcp (v_rcp ~1ulp; avoids the ~10-inst precise-div sequence)
  float si = x * __builtin_amdgcn_rcpf(1.0f + __expf(-x));
  a0 = fmaf(si, w[40], a0);
  a0 = fmaf(B0, w[0], a0); a0 = fmaf(B1, w[1], a0); a0 = fmaf(B2, w[2], a0); a0 = fmaf(B3, w[3], a0);
  a0 = fmaf(B4, w[4], a0); a0 = fmaf(B5v, w[5], a0); a0 = fmaf(B6, w[6], a0); a0 = fmaf(B7, w[7], a0);
  a1 = fmaf(si, w[41], a1);
  a1 = fmaf(B0, w[8], a1); a1 = fmaf(B1, w[9], a1); a1 = fmaf(B2, w[10], a1); a1 = fmaf(B3, w[11], a1);
  a1 = fmaf(B4, w[12], a1); a1 = fmaf(B5v, w[13], a1); a1 = fmaf(B6, w[14], a1); a1 = fmaf(B7, w[15], a1);
  a2 = fmaf(si, w[42], a2);
  a2 = fmaf(B0, w[16], a2); a2 = fmaf(B1, w[17], a2); a2 = fmaf(B2, w[18], a2); a2 = fmaf(B3, w[19], a2);
  a2 = fmaf(B4, w[20], a2); a2 = fmaf(B5v, w[21], a2); a2 = fmaf(B6, w[22], a2); a2 = fmaf(B7, w[23], a2);
  a3 = fmaf(si, w[43], a3);
  a3 = fmaf(B0, w[24], a3); a3 = fmaf(B1, w[25], a3); a3 = fmaf(B2, w[26], a3); a3 = fmaf(B3, w[27], a3);
  a3 = fmaf(B4, w[28], a3); a3 = fmaf(B5v, w[29], a3); a3 = fmaf(B6, w[30], a3); a3 = fmaf(B7, w[31], a3);
  a4 = fmaf(si, w[44], a4);
  a4 = fmaf(B0, w[32], a4); a4 = fmaf(B1, w[33], a4); a4 = fmaf(B2, w[34], a4); a4 = fmaf(B3, w[35], a4);
  a4 = fmaf(B4, w[36], a4); a4 = fmaf(B5v, w[37], a4); a4 = fmaf(B6, w[38], a4); a4 = fmaf(B7, w[39], a4);
}

// ---------------------------------------------------------------- K1: layer 1
// grid = RGROUPS*NCHUNK blocks of 256. block (rg,c): rows rg*64..+63,
// i in [c*128, +128), 4 waves x 32 i. lane <-> row. Weight addresses are
// forced wave-uniform via readfirstlane so the 45 weight loads scalarize.
__global__ __launch_bounds__(256, 4) void k1_layer1(const float* __restrict__ x,
                                                    const float* __restrict__ w1p,
                                                    float* __restrict__ hp) {
  __shared__ float part[4 * 320];
  int tid  = threadIdx.x;
  int wv   = tid >> 6, lane = tid & 63;
  int bid  = blockIdx.x;
  int rg   = bid >> 3, c = bid & 7;
  int wvu  = __builtin_amdgcn_readfirstlane(wv);   // wave-uniform wave id
  int i0   = c * 128 + wvu * 32;
  const float* xp = x + (size_t)(rg * 64 + lane) * IN1 + i0;
  const float* wb = w1p + (size_t)i0 * WPACK;      // uniform -> scalar loads
  float a0 = 0.f, a1 = 0.f, a2 = 0.f, a3 = 0.f, a4 = 0.f;
#pragma unroll 2
  for (int s = 0; s < 8; ++s) {
    float4 xv = reinterpret_cast<const float4*>(xp)[s];
    const float* w = wb + (size_t)s * 4 * WPACK;
    kan1_elem(xv.x, w,             a0, a1, a2, a3, a4);
    kan1_elem(xv.y, w + WPACK,     a0, a1, a2, a3, a4);
    kan1_elem(xv.z, w + 2 * WPACK, a0, a1, a2, a3, a4);
    kan1_elem(xv.w, w + 3 * WPACK, a0, a1, a2, a3, a4);
  }
  float* pr = part + wv * 320 + lane * 5;
  pr[0] = a0; pr[1] = a1; pr[2] = a2; pr[3] = a3; pr[4] = a4;
  __syncthreads();
  // store slab in [o][row] layout: t = o*64 + row  (coalesced reads in K2)
  for (int t = tid; t < 320; t += 256) {
    int row = t & 63, o = t >> 6;
    float s = part[row * 5 + o] + part[320 + row * 5 + o] +
              part[640 + row * 5 + o] + part[960 + row * 5 + o];
    hp[(size_t)bid * 320 + t] = s;
  }
}

// ------------------------------------------- generic bases (reference-style)
__device__ __forceinline__ void bases10(float xv, float* bb) {
  float v = fmaf(xv, 2.5f, 7.5f);
  float b[15];
#pragma unroll
  for (int j = 0; j < 15; ++j)
    b[j] = (v >= (float)j && v < (float)(j + 1)) ? 1.0f : 0.0f;
#pragma unroll
  for (int d = 1; d <= 5; ++d) {
    const float inv = 1.0f / (float)d;
#pragma unroll
    for (int j = 0; j + d < 15; ++j) {
      float left  = (v - (float)j) * inv;
      float right = ((float)(j + d + 1) - v) * inv;
      b[j] = left * b[j] + right * b[j + 1];
    }
  }
#pragma unroll
  for (int k = 0; k < 10; ++k) bb[k] = b[k];
}

// ---------------------------------------------------------------- K2: tail
// 1024 blocks x 256 threads; block <-> 16 rows (4 blocks/CU, 16 waves/CU for
// latency hiding). Phases parallel; LDS strides padded (<=2-way, free).
__global__ __launch_bounds__(256) void k2_tail(const float* __restrict__ hp,
                        const float* __restrict__ Wb2, const float* __restrict__ Ws2,
                        const float* __restrict__ Wb3, const float* __restrict__ Ws3,
                        float* __restrict__ out) {
  __shared__ float lsi1[16 * 5];
  __shared__ float lb1 [16 * 55];   // [row][i*11+k]
  __shared__ float lsi2[16 * 5];
  __shared__ float lb2 [16 * 55];
  __shared__ float llog[16 * 65];   // [row][o]
  __shared__ float lred[16 * 16];   // [q][row]
  __shared__ float lmx [16];
  __shared__ float linv[16];
  int tid  = threadIdx.x;
  int bg   = blockIdx.x;            // 0..1023, 16 rows each
  int rg64 = bg >> 2;
  int sub  = (bg & 3) * 16;

  // Phase A: reduce 8 chunk partials -> h1 ; silu + bases -> LDS. (row,i) on 80 thr.
  if (tid < 80) {
    int row = tid & 15, i = tid >> 4;
    float s = 0.f;
#pragma unroll
    for (int c = 0; c < NCHUNK; ++c)
      s += hp[(size_t)(rg64 * NCHUNK + c) * 320 + i * 64 + sub + row];
    lsi1[row * 5 + i] = s / (1.0f + __expf(-s));
    float bb[10];
    bases10(s, bb);
#pragma unroll
    for (int k = 0; k < 10; ++k) lb1[row * 55 + i * 11 + k] = bb[k];
  }
  __syncthreads();

  // Phase B: layer 2 (row,o) on 80 threads; silu+bases of own h2.
  if (tid < 80) {
    int row = tid & 15, o = tid >> 4;
    float acc = 0.f;
#pragma unroll
    for (int i = 0; i < 5; ++i) {
      acc = fmaf(lsi1[row * 5 + i], Wb2[i * 5 + o], acc);
#pragma unroll
      for (int k = 0; k < 10; ++k)
        acc = fmaf(lb1[row * 55 + i * 11 + k], Ws2[(i * 5 + o) * 10 + k], acc);
    }
    lsi2[row * 5 + o] = acc / (1.0f + __expf(-acc));
    float bb[10];
    bases10(acc, bb);
#pragma unroll
    for (int k = 0; k < 10; ++k) lb2[row * 55 + o * 11 + k] = bb[k];
  }
  __syncthreads();

  // Phase C: logits. thread -> (o = tid&63, 4 rows). Row-uniform LDS reads.
  {
    int o  = tid & 63;
    int r0 = (tid >> 6) * 4;
    float lg[4] = {0.f, 0.f, 0.f, 0.f};
#pragma unroll
    for (int i = 0; i < 5; ++i) {
      float wbv = Wb3[i * 64 + o];
      float w[10];
#pragma unroll
      for (int k = 0; k < 10; ++k) w[k] = Ws3[(i * 64 + o) * 10 + k];
#pragma unroll
      for (int rr = 0; rr < 4; ++rr) {
        int row = r0 + rr;
        lg[rr] = fmaf(lsi2[row * 5 + i], wbv, lg[rr]);
#pragma unroll
        for (int k = 0; k < 10; ++k)
          lg[rr] = fmaf(lb2[row * 55 + i * 11 + k], w[k], lg[rr]);
      }
    }
#pragma unroll
    for (int rr = 0; rr < 4; ++rr) llog[(r0 + rr) * 65 + o] = lg[rr];
  }
  __syncthreads();

  // Phase D: softmax, 16 threads per row (q = tid>>4 handles 4 outs).
  int q = tid >> 4, row = tid & 15;
  {
    float m = -1e30f;
#pragma unroll
    for (int oo = 0; oo < 4; ++oo)
      m = fmaxf(m, llog[row * 65 + q * 4 + oo]);
    lred[q * 16 + row] = m;
  }
  __syncthreads();
  if (tid < 16) {
    float m = -1e30f;
#pragma unroll
    for (int k = 0; k < 16; ++k) m = fmaxf(m, lred[k * 16 + tid]);
    lmx[tid] = m;
  }
  __syncthreads();
  {
    float m = lmx[row];
    float s = 0.f;
#pragma unroll
    for (int oo = 0; oo < 4; ++oo) {
      int idx = row * 65 + q * 4 + oo;
      float e = __expf(llog[idx] - m);
      llog[idx] = e;
      s += e;
    }
    lred[q * 16 + row] = s;
  }
  __syncthreads();
  if (tid < 16) {
    float s = 0.f;
#pragma unroll
    for (int k = 0; k < 16; ++k) s += lred[k * 16 + tid];
    linv[tid] = 1.0f / s;
  }
  __syncthreads();
  // coalesced store: 16 rows x 64 outs = 1024 floats, 4 per thread
#pragma unroll
  for (int uu = 0; uu < 4; ++uu) {
    int u = tid + uu * 256;
    int r = u >> 6, o = u & 63;
    out[(size_t)(bg * 16 + r) * 64 + o] = llog[r * 65 + o] * linv[r];
  }
}

// ---------------------------------------------------------------- launch
extern "C" void kernel_launch(void* const* d_in, const int* in_sizes, int n_in,
                              void* d_out, int out_size, void* d_ws, size_t ws_size,
                              hipStream_t stream) {
  const float* x   = (const float*)d_in[0];
  const float* Wb1 = (const float*)d_in[1];
  const float* Ws1 = (const float*)d_in[2];
  const float* Wb2 = (const float*)d_in[3];
  const float* Ws2 = (const float*)d_in[4];
  const float* Wb3 = (const float*)d_in[5];
  const float* Ws3 = (const float*)d_in[6];
  float* out = (float*)d_out;

  float* w1p = (float*)d_ws;                       // 1024*48 floats = 192 KiB
  float* hp  = w1p + (size_t)IN1 * WPACK;          // 2048*320 floats = 2.5 MiB

  hipLaunchKernelGGL(k0_pack, dim3((IN1 * WPACK) / 256), dim3(256), 0, stream,
                     Wb1, Ws1, w1p);
  hipLaunchKernelGGL(k1_layer1, dim3(RGROUPS * NCHUNK), dim3(256), 0, stream,
                     x, w1p, hp);
  hipLaunchKernelGGL(k2_tail, dim3(NROWS / 16), dim3(256), 0, stream,
                     hp, Wb2, Ws2, Wb3, Ws3, out);
}